// Round 9
// baseline (2827.046 us; speedup 1.0000x reference)
//
#include <hip/hip_runtime.h>
#include <cstdint>
#include <cstddef>
#include <cmath>

typedef __bf16 bf16_t;
typedef __bf16 bf16x8 __attribute__((ext_vector_type(8)));
typedef float floatx4 __attribute__((ext_vector_type(4)));

#define AS1 __attribute__((address_space(1)))
#define AS3 __attribute__((address_space(3)))

__device__ __forceinline__ void gload_lds16(const bf16_t* g, bf16_t* l) {
    __builtin_amdgcn_global_load_lds((AS1 void*)(uintptr_t)(g), (AS3 void*)(l), 16, 0, 0);
}

__device__ __forceinline__ float sigf(float x) { return 1.0f / (1.0f + __expf(-x)); }
__device__ __forceinline__ float tanhfast(float x) { return 1.0f - 2.0f / (__expf(2.0f * x) + 1.0f); }

// ---- cheap inter-block barrier ----
// R7 post-mortem: polling with atomicAdd(bar,0) is an exclusive RMW -> 256
// spinners serialize on one line AND starve the incrementers (~45 us/barrier).
// Fix: increment = release fetch_add (device scope); poll = agent-scope
// ACQUIRE *load* (coherent read, no ownership, no serialization).
__device__ __forceinline__ void gbar(int* bar, int target)
{
    __syncthreads();
    if (threadIdx.x == 0) {
        __threadfence();   // agent release of this block's prior writes
        __hip_atomic_fetch_add(bar, 1, __ATOMIC_RELEASE, __HIP_MEMORY_SCOPE_AGENT);
        while (__hip_atomic_load(bar, __ATOMIC_ACQUIRE, __HIP_MEMORY_SCOPE_AGENT) < target)
            __builtin_amdgcn_s_sleep(4);
    }
    __syncthreads();
    __threadfence();       // agent acquire: drop stale cached lines
}

// ================= GEMM+LSTM tile (device fn; proven in R6 mega) =================
// gates = A(M,1152) @ W(N,1152)^T + bias, LSTM cell fused in epilogue.
// A split at xlim (mult of 64): cols [0,xlim) from Ax, rest from Ah (ping-pong).
// Gate-interleaved W: lane's acc[i][0..3] = (i,f,g,o) of element
// e = ((n0+wn)>>2)+(lane&15). LDS XOR swizzle: phys 16B chunk = logical^(row&7);
// staging keeps linear base+lane*16 LDS addrs (global_load_lds requirement)
// by permuting per-lane global addresses. c transposed [e][4096] -> float4.
template<int BM>
__device__ __forceinline__ void gemm_lstm_phase(
    const bf16_t* __restrict__ Ax, int ldX, int xlim,
    const bf16_t* __restrict__ Ah, int ldHin,
    const bf16_t* __restrict__ W, const float* __restrict__ bias,
    float* __restrict__ c,
    bf16_t* __restrict__ hb, float* __restrict__ hf, int ldHo, int relu,
    int bx, int by, bf16_t* As, bf16_t* Bs)
{
    constexpr int AI = BM / 32;
    constexpr int K  = 1152;
    const int tid  = threadIdx.x;
    const int lane = tid & 63;
    const int w    = tid >> 6;
    const int wm   = (w & 1) * (BM / 2);
    const int wn   = (w >> 1) * 64;
    const int m0   = by * BM;
    const int n0   = bx * 128;

    floatx4 zero = {0.0f, 0.0f, 0.0f, 0.0f};
    floatx4 acc[AI][4];
#pragma unroll
    for (int i = 0; i < AI; ++i)
#pragma unroll
        for (int j = 0; j < 4; ++j) acc[i][j] = zero;

    const int srow = lane >> 3;
    const int sk   = ((lane & 7) ^ srow) * 8;
    const int fr   = lane & 15;
    const int fx   = fr & 7;

    for (int k0 = 0; k0 < K; k0 += 64) {
        const bf16_t* Abase; int lda, koff;
        if (k0 < xlim) { Abase = Ax; lda = ldX;   koff = k0; }
        else           { Abase = Ah; lda = ldHin; koff = k0 - xlim; }
        const bf16_t* Ag = Abase + (size_t)(m0 + srow) * lda + sk + koff;
        const bf16_t* Bg = W + (size_t)(n0 + srow) * 1152 + sk + k0;
        __syncthreads();
#pragma unroll
        for (int j = 0; j < AI; ++j) {
            int r0 = (w * AI + j) * 8;
            gload_lds16(Ag + (size_t)r0 * lda, As + r0 * 64 + lane * 8);
        }
#pragma unroll
        for (int j = 0; j < 4; ++j) {
            int r0 = (w * 4 + j) * 8;
            gload_lds16(Bg + (size_t)r0 * 1152, Bs + r0 * 64 + lane * 8);
        }
        __syncthreads();
#pragma unroll
        for (int kk = 0; kk < 64; kk += 32) {
            const int pc = ((((kk >> 3) + (lane >> 4)) ^ fx) << 3);
            bf16x8 af[AI], bfr[4];
#pragma unroll
            for (int i = 0; i < AI; ++i)
                af[i] = *(const bf16x8*)(As + (wm + i * 16 + fr) * 64 + pc);
#pragma unroll
            for (int j = 0; j < 4; ++j)
                bfr[j] = *(const bf16x8*)(Bs + (wn + j * 16 + fr) * 64 + pc);
#pragma unroll
            for (int i = 0; i < AI; ++i)
#pragma unroll
                for (int j = 0; j < 4; ++j)
                    acc[i][j] = __builtin_amdgcn_mfma_f32_16x16x32_bf16(af[i], bfr[j], acc[i][j], 0, 0, 0);
        }
    }

    const int crow = (lane >> 4) * 4;
    const int ccol = lane & 15;
    const int e    = ((n0 + wn) >> 2) + ccol;
    float bi[4];
#pragma unroll
    for (int j = 0; j < 4; ++j) bi[j] = bias[n0 + wn + j * 16 + ccol];

#pragma unroll
    for (int i = 0; i < AI; ++i) {
        int tb = m0 + wm + i * 16 + crow;
        floatx4* cp = (floatx4*)(c + (size_t)e * 4096 + tb);
        floatx4 cold = *cp, cnew;
        float hv[4];
#pragma unroll
        for (int r = 0; r < 4; ++r) {
            float iv = acc[i][0][r] + bi[0];
            float fv = acc[i][1][r] + bi[1];
            float gv = acc[i][2][r] + bi[2];
            float ov = acc[i][3][r] + bi[3];
            float cv = sigf(fv) * cold[r] + sigf(iv) * tanhfast(gv);
            cnew[r] = cv;
            float h = sigf(ov) * tanhfast(cv);
            if (relu) h = fmaxf(h, 0.0f);
            hv[r] = h;
        }
        *cp = cnew;
        if (hb) {
#pragma unroll
            for (int r = 0; r < 4; ++r) hb[(size_t)(tb + r) * ldHo + e] = (bf16_t)hv[r];
        } else {
#pragma unroll
            for (int r = 0; r < 4; ++r) hf[(size_t)(tb + r) * ldHo + e] = hv[r];
        }
    }
}

// ================= ONE persistent kernel: prep -> enc x4 -> dec x4 -> softmax ===========
// 1024 blocks x 256 thr, 4 blocks/CU co-resident (proven: R6 coop launch of the
// identical-footprint kernel succeeded with all 1024 resident). Phases joined
// by gbar (bar pre-zeroed by hipMemsetAsync). Decoder keeps c in registers.
__global__ __launch_bounds__(256, 4)
void fused(const float* __restrict__ x,
           const float* __restrict__ eWih, const float* __restrict__ eWhh,
           const float* __restrict__ ebih, const float* __restrict__ ebhh,
           const float* __restrict__ dWih, const float* __restrict__ dWhh,
           const float* __restrict__ dbih, const float* __restrict__ dbhh,
           char* __restrict__ ws, float* __restrict__ out, int* __restrict__ bar)
{
    __shared__ bf16_t As[128 * 64];
    __shared__ bf16_t Bs[128 * 64];

    bf16_t* Xpad = (bf16_t*)(ws);                 // 4096x128 bf16
    bf16_t* He0  = (bf16_t*)(ws + 1048576);       // 4096x1024 bf16
    bf16_t* He1  = (bf16_t*)(ws + 9437184);
    bf16_t* E    = (bf16_t*)(ws + 17825792);
    bf16_t* Hd0  = (bf16_t*)(ws + 26214400);      // 4096x128 bf16
    bf16_t* Hd1  = (bf16_t*)(ws + 27262976);
    bf16_t* Wenc = (bf16_t*)(ws + 28311552);      // 4x4096x1152 bf16
    bf16_t* Wdec = (bf16_t*)(ws + 66060288);      // 4x512x1152 bf16
    float*  bse  = (float*) (ws + 70778880);      // 16384
    float*  bsd  = (float*) (ws + 70844416);      // 2048
    float*  cenc = (float*) (ws + 70852608);      // [1024][4096] f32
    float*  hdec = (float*) (ws + 87629824);      // 4096x128 f32

    const int G    = gridDim.x;                   // 1024
    const int bid  = blockIdx.x;
    const int gtid = bid * 256 + threadIdx.x;
    const int P    = G * 256;
    int phase = 0;

    // ---- phase 0: pack weights/bias/x, zero states ----
    for (int u = gtid; u < 16384 * 144; u += P) {
        int row = u / 144, grp = u - row * 144;
        int l = row >> 12, p = row & 4095;
        int g = (p >> 4) & 3, e = ((p >> 6) << 4) + (p & 15);
        int c0 = grp * 8;
        float v[8];
#pragma unroll
        for (int k = 0; k < 8; ++k) v[k] = 0.0f;
        if (e < 1000) {
            size_t r = (size_t)l * 4000 + g * 1000 + e;
            if (c0 >= 128 && c0 < 1128) {
                const float* src = eWhh + r * 1000 + (c0 - 128);
                float4 a = *(const float4*)src;
                float4 b = *(const float4*)(src + 4);
                v[0]=a.x; v[1]=a.y; v[2]=a.z; v[3]=a.w; v[4]=b.x; v[5]=b.y; v[6]=b.z; v[7]=b.w;
            } else if (c0 < 128) {
                const float* src = eWih + r * 101;
#pragma unroll
                for (int k = 0; k < 8; ++k) { int cc = c0 + k; if (cc < 101) v[k] = src[cc]; }
            }
        }
        bf16x8 o;
#pragma unroll
        for (int k = 0; k < 8; ++k) o[k] = (bf16_t)v[k];
        *(bf16x8*)(Wenc + (size_t)row * 1152 + c0) = o;
    }
    for (int u = gtid; u < 2048 * 144; u += P) {
        int row = u / 144, grp = u - row * 144;
        int l = row >> 9, p = row & 511;
        int g = (p >> 4) & 3, e = ((p >> 6) << 4) + (p & 15);
        int c0 = grp * 8;
        float v[8];
#pragma unroll
        for (int k = 0; k < 8; ++k) v[k] = 0.0f;
        if (e < 101) {
            size_t r = (size_t)l * 404 + g * 101 + e;
            if (c0 < 1000) {
                const float* src = dWih + r * 1000 + c0;
                float4 a = *(const float4*)src;
                float4 b = *(const float4*)(src + 4);
                v[0]=a.x; v[1]=a.y; v[2]=a.z; v[3]=a.w; v[4]=b.x; v[5]=b.y; v[6]=b.z; v[7]=b.w;
            } else if (c0 >= 1024 && c0 < 1128) {
                const float* src = dWhh + r * 101;
#pragma unroll
                for (int k = 0; k < 8; ++k) { int cc = c0 + k; if (cc < 1125) v[k] = src[cc - 1024]; }
            }
        }
        bf16x8 o;
#pragma unroll
        for (int k = 0; k < 8; ++k) o[k] = (bf16_t)v[k];
        *(bf16x8*)(Wdec + (size_t)row * 1152 + c0) = o;
    }
    for (int u = gtid; u < 65536; u += P) {
        int row = u >> 4, c0 = (u & 15) * 8;
        float v[8];
#pragma unroll
        for (int k = 0; k < 8; ++k) v[k] = 0.0f;
        if (c0 < 101) {
            const float* src = x + (size_t)row * 101;
#pragma unroll
            for (int k = 0; k < 8; ++k) { int cc = c0 + k; if (cc < 101) v[k] = src[cc]; }
        }
        bf16x8 o;
#pragma unroll
        for (int k = 0; k < 8; ++k) o[k] = (bf16_t)v[k];
        *(bf16x8*)(Xpad + (size_t)row * 128 + c0) = o;
    }
    {
        float4 z = {0.0f, 0.0f, 0.0f, 0.0f};
        for (int u = gtid; u < 524288 + 65536 + 1048576; u += P) {
            if      (u < 524288)           ((float4*)He0)[u] = z;
            else if (u < 524288 + 65536)   ((float4*)Hd0)[u - 524288] = z;
            else                           ((float4*)cenc)[u - 524288 - 65536] = z;
        }
    }
    for (int u = gtid; u < 18432; u += P) {
        if (u < 16384) {
            int l = u >> 12, p = u & 4095;
            int g = (p >> 4) & 3, e = ((p >> 6) << 4) + (p & 15);
            bse[u] = (e < 1000) ? (ebih[l * 4000 + g * 1000 + e] + ebhh[l * 4000 + g * 1000 + e]) : 0.0f;
        } else {
            int k = u - 16384;
            int l = k >> 9, p = k & 511;
            int g = (p >> 4) & 3, e = ((p >> 6) << 4) + (p & 15);
            bsd[k] = (e < 101) ? (dbih[l * 404 + g * 101 + e] + dbhh[l * 404 + g * 101 + e]) : 0.0f;
        }
    }
    gbar(bar, ++phase * G);

    // ---- encoder: 4 layers, 1024 tiles (32x32), one tile per block ----
    for (int l = 0; l < 4; ++l) {
        const bf16_t* Hin = (l & 1) ? He1 : He0;
        bf16_t* hbout; int relu = 0;
        if (l < 3) hbout = (l & 1) ? He0 : He1;
        else { hbout = E; relu = 1; }
        gemm_lstm_phase<128>(Xpad, 128, 128, Hin, 1024,
                             Wenc + (size_t)l * 4096 * 1152, bse + l * 4096,
                             cenc, hbout, nullptr, 1024, relu,
                             bid & 31, bid >> 5, As, Bs);
        gbar(bar, ++phase * G);
    }

    // ---- decoder: 4 layers, 256 tiles (4 x 64, BM=64); c in registers ----
    {
        const bool active = (bid & 3) == 0;       // spread tiles across CUs
        const int t   = bid >> 2;                 // 0..255
        const int bx  = t & 3, by = t >> 2;
        const int lane = threadIdx.x & 63;
        const int w    = threadIdx.x >> 6;
        const int wm   = (w & 1) * 32;
        const int wn   = (w >> 1) * 64;
        const int m0   = by * 64;
        const int n0   = bx * 128;
        const int srow = lane >> 3;
        const int sk   = ((lane & 7) ^ srow) * 8;
        const int fr   = lane & 15;
        const int fx   = fr & 7;
        const int crow = (lane >> 4) * 4;
        const int ccol = lane & 15;
        const int e    = ((n0 + wn) >> 2) + ccol;

        floatx4 zero = {0.0f, 0.0f, 0.0f, 0.0f};
        floatx4 creg[2] = {zero, zero};

        for (int l = 0; l < 4; ++l) {
            if (active) {
                const bf16_t* W   = Wdec + (size_t)l * 512 * 1152;
                const bf16_t* Hin = (l & 1) ? Hd1 : Hd0;
                floatx4 acc[2][4];
#pragma unroll
                for (int i = 0; i < 2; ++i)
#pragma unroll
                    for (int j = 0; j < 4; ++j) acc[i][j] = zero;

                for (int k0 = 0; k0 < 1152; k0 += 64) {
                    const bf16_t* Abase; int lda, koff;
                    if (k0 < 1024) { Abase = E;   lda = 1024; koff = k0; }
                    else           { Abase = Hin; lda = 128;  koff = k0 - 1024; }
                    const bf16_t* Ag = Abase + (size_t)(m0 + srow) * lda + sk + koff;
                    const bf16_t* Bg = W + (size_t)(n0 + srow) * 1152 + sk + k0;
                    __syncthreads();
#pragma unroll
                    for (int j = 0; j < 2; ++j) {
                        int r0 = (w * 2 + j) * 8;
                        gload_lds16(Ag + (size_t)r0 * lda, As + r0 * 64 + lane * 8);
                    }
#pragma unroll
                    for (int j = 0; j < 4; ++j) {
                        int r0 = (w * 4 + j) * 8;
                        gload_lds16(Bg + (size_t)r0 * 1152, Bs + r0 * 64 + lane * 8);
                    }
                    __syncthreads();
#pragma unroll
                    for (int kk = 0; kk < 64; kk += 32) {
                        const int pc = ((((kk >> 3) + (lane >> 4)) ^ fx) << 3);
                        bf16x8 af[2], bfr[4];
#pragma unroll
                        for (int i = 0; i < 2; ++i)
                            af[i] = *(const bf16x8*)(As + (wm + i * 16 + fr) * 64 + pc);
#pragma unroll
                        for (int j = 0; j < 4; ++j)
                            bfr[j] = *(const bf16x8*)(Bs + (wn + j * 16 + fr) * 64 + pc);
#pragma unroll
                        for (int i = 0; i < 2; ++i)
#pragma unroll
                            for (int j = 0; j < 4; ++j)
                                acc[i][j] = __builtin_amdgcn_mfma_f32_16x16x32_bf16(af[i], bfr[j], acc[i][j], 0, 0, 0);
                    }
                }

                const float* bias = bsd + l * 512;
                float bi[4];
#pragma unroll
                for (int j = 0; j < 4; ++j) bi[j] = bias[n0 + wn + j * 16 + ccol];
                bf16_t* Hout = (l & 1) ? Hd0 : Hd1;
#pragma unroll
                for (int i = 0; i < 2; ++i) {
                    int tb = m0 + wm + i * 16 + crow;
                    floatx4 cnew;
#pragma unroll
                    for (int r = 0; r < 4; ++r) {
                        float iv = acc[i][0][r] + bi[0];
                        float fv = acc[i][1][r] + bi[1];
                        float gv = acc[i][2][r] + bi[2];
                        float ov = acc[i][3][r] + bi[3];
                        float cv = sigf(fv) * creg[i][r] + sigf(iv) * tanhfast(gv);
                        cnew[r] = cv;
                        float hv = sigf(ov) * tanhfast(cv);
                        if (l < 3) Hout[(size_t)(tb + r) * 128 + e] = (bf16_t)hv;
                        else       hdec[(size_t)(tb + r) * 128 + e] = hv;
                    }
                    creg[i] = cnew;
                }
            }
            gbar(bar, ++phase * G);
        }
    }

    // ---- log_softmax: 4096 rows, one wave per row ----
    {
        const int w    = threadIdx.x >> 6;
        const int lane = threadIdx.x & 63;
        const int row  = bid * 4 + w;
        const float* hr = hdec + (size_t)row * 128;
        float v1 = (lane < 101)      ? hr[lane]      : -INFINITY;
        float v2 = (lane + 64 < 101) ? hr[lane + 64] : -INFINITY;
        float m = fmaxf(v1, v2);
#pragma unroll
        for (int off = 32; off > 0; off >>= 1) m = fmaxf(m, __shfl_down(m, off));
        m = __shfl(m, 0);
        float ev = ((lane < 101) ? __expf(v1 - m) : 0.0f) + ((lane + 64 < 101) ? __expf(v2 - m) : 0.0f);
#pragma unroll
        for (int off = 32; off > 0; off >>= 1) ev += __shfl_down(ev, off);
        float lse = m + __logf(__shfl(ev, 0));
        float* orow = out + (size_t)row * 101;
        if (lane < 101)      orow[lane]      = v1 - lse;
        if (lane + 64 < 101) orow[lane + 64] = v2 - lse;
    }
}

extern "C" void kernel_launch(void* const* d_in, const int* in_sizes, int n_in,
                              void* d_out, int out_size, void* d_ws, size_t ws_size,
                              hipStream_t stream)
{
    (void)in_sizes; (void)n_in; (void)out_size; (void)ws_size;
    const float* x    = (const float*)d_in[0];
    const float* eWih = (const float*)d_in[1];
    const float* eWhh = (const float*)d_in[2];
    const float* ebih = (const float*)d_in[3];
    const float* ebhh = (const float*)d_in[4];
    const float* dWih = (const float*)d_in[5];
    const float* dWhh = (const float*)d_in[6];
    const float* dbih = (const float*)d_in[7];
    const float* dbhh = (const float*)d_in[8];
    char* ws = (char*)d_ws;

    int* bar = (int*)(ws + 89726976);             // after hdec (end 89,726,980)

    hipMemsetAsync(bar, 0, 4, stream);
    fused<<<1024, 256, 0, stream>>>(x, eWih, eWhh, ebih, ebhh,
                                    dWih, dWhh, dbih, dbhh,
                                    ws, (float*)d_out, bar);
}